// Round 6
// baseline (212.297 us; speedup 1.0000x reference)
//
#include <hip/hip_runtime.h>

#define Bb 2
#define Nn 256
#define Dd 128
#define Rr 32

typedef unsigned short u16;
typedef unsigned int   u32;
typedef __attribute__((ext_vector_type(8))) short bf16x8;
typedef __attribute__((ext_vector_type(4))) short bf16x4;
typedef __attribute__((ext_vector_type(4))) float f32x4;
typedef __attribute__((ext_vector_type(2))) u32   u32x2;
typedef __attribute__((ext_vector_type(4))) u32   u32x4;

// one-time bf16-transposed radial weights (fragment-order), filled by prep_kernel
__device__ u16 g_w1t[4*Dd*Rr];   // per p: W1T[dd*32 + kk] = bf16(W1[kk][dd])
__device__ u16 g_w2t[4*Dd*Dd];   // per p: W2T[dd*128 + kk] = bf16(W2[kk][dd])

__device__ __forceinline__ short f2bfs(float f){
  u32 u = __float_as_uint(f);
  u += 0x7FFFu + ((u >> 16) & 1u);   // RNE
  return (short)(u >> 16);
}
__device__ __forceinline__ u16 f2bf(float f){
  u32 u = __float_as_uint(f);
  u += 0x7FFFu + ((u >> 16) & 1u);
  return (u16)(u >> 16);
}
// packed f32x2 -> bf16x2 (RNE), one VALU op
__device__ __forceinline__ u32 cvtpk(float a, float b){
  u32 r;
  asm("v_cvt_pk_bf16_f32 %0, %1, %2" : "=v"(r) : "v"(a), "v"(b));
  return r;
}
// 3-bit LDS group swizzle for s_hid (16B granule)
__device__ __forceinline__ int swz(int j){
  return (j&3) | ((((j>>2)^(j>>3))&1)<<2);
}

// ---- prep: blocks [0,512): h = node_s @ src_w ; blocks [512,544): weight bf16-transpose
__global__ __launch_bounds__(128) void prep_kernel(
    const float* __restrict__ node_s, const float* __restrict__ src_w,
    const float* __restrict__ r0w1, const float* __restrict__ r1w1,
    const float* __restrict__ r2w1, const float* __restrict__ r3w1,
    const float* __restrict__ r0w2, const float* __restrict__ r1w2,
    const float* __restrict__ r2w2, const float* __restrict__ r3w2,
    float* __restrict__ h_out)
{
  const int bx = blockIdx.x;
  const int t  = threadIdx.x;
  if (bx < Bb*Nn){
    __shared__ float s_row[Dd];
    s_row[t] = node_s[(size_t)bx*Dd + t];
    __syncthreads();
    float acc = 0.f;
    #pragma unroll 8
    for (int k=0;k<Dd;k++) acc += s_row[k]*src_w[k*Dd + t];
    h_out[(size_t)bx*Dd + t] = acc;
  } else {
    const int kb = bx - Bb*Nn;          // 0..31
    const int p  = kb >> 3, sl = kb & 7;
    const float* W1 = (p==0)?r0w1:(p==1)?r1w1:(p==2)?r2w1:r3w1;
    const float* W2 = (p==0)?r0w2:(p==1)?r1w2:(p==2)?r2w2:r3w2;
    u16* W1T = g_w1t + p*Dd*Rr;
    u16* W2T = g_w2t + p*Dd*Dd;
    // coalesced reads, scattered writes (stores don't stall)
    #pragma unroll
    for (int it=0; it<4; it++){
      int in = sl*512 + it*128 + t;                  // in = kk*Dd + dd
      W1T[(in & 127)*Rr + (in >> 7)] = f2bf(W1[in]);
    }
    #pragma unroll
    for (int it=0; it<16; it++){
      int in = sl*2048 + it*128 + t;                 // in = kk*Dd + dd
      W2T[(in & 127)*Dd + (in >> 7)] = f2bf(W2[in]);
    }
  }
}

// ---- main: 4 waves/block (256 thr), 4 blocks/CU (LDS 40,096 B). Wave w owns
// d-cols [w*32,+32) and ALL j (accred complete per wave -> no pair-merge).
// Per chunk (64 j): GEMM1^T -> SiLU -> s_hid (single buf, XOR-swizzled) ->
// barrier -> GEMM2 with permuted m-tiles (g in {0,1}, tile (g,mm) row x holds
// j = g*32 + (x>>2)*8 + mm*4 + (x&3)) so each lane's epilogue G values form
// its j-reduction B-fragment in registers. launch_bounds targets 128 VGPR to
// avoid the 64-VGPR+scratch-spill the 512-thread variants exhibited.
__global__ __launch_bounds__(256)
__attribute__((amdgpu_waves_per_eu(4,4)))
void se3_mfma10(
    const float* __restrict__ node_v,
    const float* __restrict__ rbf,
    const float* __restrict__ r_hat,
    const float* __restrict__ maskp,
    const float* __restrict__ r0b1, const float* __restrict__ r0b2,
    const float* __restrict__ r1b1, const float* __restrict__ r1b2,
    const float* __restrict__ r2b1, const float* __restrict__ r2b2,
    const float* __restrict__ r3b1, const float* __restrict__ r3b2,
    const float* __restrict__ ln_g, const float* __restrict__ ln_b,
    const float* __restrict__ out_w, const float* __restrict__ out_b,
    const float* __restrict__ v_scale, const float* __restrict__ t_scale,
    const float* __restrict__ h_ws,
    float* __restrict__ out_s, float* __restrict__ out_v, float* __restrict__ out_t)
{
  __shared__ u16 s_rbf[Nn*36];     // 18432: rbf bf16, row stride 36 (bank-spread)
  __shared__ u16 s_hid[64*128];    // 16384: single buffer, XOR-swizzled
  __shared__ u16 s_YT[10*264];     //  5280: rows 0=mask,1-3=Y1*m,4-8=Y2*m,9=mask
  // total 40,096 B -> 4 blocks/CU. End-phase scratch aliases dead s_hid:
  float* s_msg  = (float*)s_hid;         // [128]
  float* s_xn   = s_msg + Dd;            // [128]
  float* s_part = s_xn  + Dd;            // [256]
  float* s_mv   = s_part + 2*Dd;         // [2]

  const int tid  = threadIdx.x;
  const int bi   = blockIdx.x;            // b*N + i
  const int b    = bi >> 8;
  const int lane = tid & 63;
  const int w    = tid >> 6;              // wave 0..3
  const int q    = lane >> 4;
  const int cc   = lane & 15;
  const int dbase= w*32;

  // ---- setup: stacked-Y rows (mask folded) ----
  {
    int j = tid;
    size_t pidx = (size_t)bi*Nn + j;
    float mk = maskp[pidx];
    float x = r_hat[pidx*3+0];
    float y = r_hat[pidx*3+1];
    float z = r_hat[pidx*3+2];
    const float SQ3=1.7320508075688772f;
    const float C15=3.8729833462074170f;
    const float C5H=1.1180339887498949f;
    s_YT[0*264+j]=f2bf(mk);
    s_YT[1*264+j]=f2bf(SQ3*x*mk);
    s_YT[2*264+j]=f2bf(SQ3*y*mk);
    s_YT[3*264+j]=f2bf(SQ3*z*mk);
    s_YT[4*264+j]=f2bf(C15*x*y*mk);
    s_YT[5*264+j]=f2bf(C15*y*z*mk);
    s_YT[6*264+j]=f2bf(C5H*(3.f*z*z-1.f)*mk);
    s_YT[7*264+j]=f2bf(C15*x*z*mk);
    s_YT[8*264+j]=f2bf(0.5f*C15*(x*x-y*y)*mk);
    s_YT[9*264+j]=f2bf(mk);
  }

  const float* rbf_blk = rbf + (size_t)bi*Nn*Rr;
  const float* rh_blk  = r_hat + (size_t)bi*Nn*3;
  const float* hb      = h_ws + (size_t)b*Nn*Dd;

  // ---- stage rbf as bf16 (row stride 36): packed pairs ----
  for (int idx=tid; idx<Nn*Rr/2; idx+=256){
    int j = idx >> 4, r2 = (idx & 15)*2;
    const float* src = &rbf_blk[j*Rr + r2];
    float v0 = src[0], v1 = src[1];
    *(u32*)&s_rbf[j*36 + r2] = cvtpk(v0, v1);
  }

  // ---- node_v B-fragments for the dot MFMA ----
  bf16x8 vBf[2];
  {
    const float* nv = node_v + (size_t)bi*3*Dd;
    #pragma unroll
    for (int nt=0;nt<2;nt++){
      int dd = dbase+nt*16+cc;
      bf16x8 t = {0,0,0,0,0,0,0,0};
      if (q==0){
        t[0]=f2bfs(nv[0*Dd+dd]);
        t[1]=f2bfs(nv[1*Dd+dd]);
        t[2]=f2bfs(nv[2*Dd+dd]);
      }
      vBf[nt]=t;
    }
  }

  const f32x4 zf = {0.f,0.f,0.f,0.f};
  f32x4 accred[2] = {zf, zf};
  const u16* ytrow = &s_YT[(cc<10?cc:9)*264];

  #pragma unroll 1
  for (int p=0;p<4;p++){
    const float* B1p = (p==0)?r0b1:(p==1)?r1b1:(p==2)?r2b1:r3b1;
    const float* B2p = (p==0)?r0b2:(p==1)?r1b2:(p==2)?r2b2:r3b2;
    const u16* W1T = g_w1t + p*Dd*Rr;
    const u16* W2T = g_w2t + p*Dd*Dd;
    const int lo = (p==0)?0:(p==1)?1:(p==2)?4:9;
    const int hi = (p==0)?0:(p==1)?3:(p==2)?8:9;
    const u32 gmask = (cc>=lo && cc<=hi) ? 0xFFFFFFFFu : 0u;

    // per-p weight fragments (vector loads from prepped layout)
    bf16x8 w1f[2];
    bf16x8 w2f[2][4];
    f32x4  b1v4[2];
    float  b2v[2];
    #pragma unroll
    for (int nt=0;nt<2;nt++){
      int dd = dbase+nt*16+cc;
      b1v4[nt] = *(const f32x4*)&B1p[dbase + nt*16 + q*4];
      b2v[nt]=B2p[dd];
      w1f[nt] = *(const bf16x8*)&W1T[dd*Rr + q*8];
      #pragma unroll
      for (int ks=0;ks<4;ks++)
        w2f[nt][ks] = *(const bf16x8*)&W2T[dd*Dd + ks*32 + q*8];
    }

    #pragma unroll 1
    for (int ch=0; ch<4; ch++){
      __syncthreads();                 // s_hid free (prev chunk consumed) / staging visible
      // ---- GEMM1^T: A = w1f (rows d), B = rbf frag (cols j); all 4 j-tiles ----
      #pragma unroll 1
      for (int jt=0;jt<4;jt++){
        const int jrow = jt*16 + cc;                 // j within chunk
        const u16* bp = &s_rbf[(ch*64 + jrow)*36 + q*8];
        bf16x4 lo4 = *(const bf16x4*)bp;
        bf16x4 hi4 = *(const bf16x4*)(bp+4);
        bf16x8 rbff = {lo4[0],lo4[1],lo4[2],lo4[3],hi4[0],hi4[1],hi4[2],hi4[3]};
        #pragma unroll
        for (int nt=0;nt<2;nt++){
          f32x4 hc = __builtin_amdgcn_mfma_f32_16x16x32_bf16(w1f[nt], rbff, zf, 0,0,0);
          float s[4];
          #pragma unroll
          for (int r=0;r<4;r++){
            float x  = hc[r] + b1v4[nt][r];
            float e  = __expf(-x);
            s[r]     = x*__builtin_amdgcn_rcpf(1.f+e);
          }
          u32x2 pk = { cvtpk(s[0], s[1]), cvtpk(s[2], s[3]) };
          const int c0 = w*4 + nt*2 + (q>>1);        // 16B d-group index 0..15
          *(u32x2*)&s_hid[jrow*128 + ((c0 ^ swz(jrow))<<3) + (q&1)*4] = pk;
        }
      }
      __syncthreads();                 // hidden ready (all waves)

      // ---- GEMM2 over permuted tiles, both 32-j groups ----
      #pragma unroll 1
      for (int g=0; g<2; g++){
        u32 bB[2][4];
        #pragma unroll 1
        for (int mm=0;mm<2;mm++){
          // tile (g,mm) A-row cc <-> j-local jp
          const int jp = g*32 + ((cc>>2)<<3) + mm*4 + (cc&3);
          bf16x8 af[4];
          #pragma unroll
          for (int ks=0;ks<4;ks++)
            af[ks] = *(const bf16x8*)&s_hid[jp*128 + (((ks*4+q) ^ swz(jp))<<3)];

          f32x4 dotC[2];
          if (p==3){                   // dot(v, Y1): recompute Y1 from r_hat (L2)
            bf16x8 aY = {0,0,0,0,0,0,0,0};
            if (q==0){
              const float SQ3=1.7320508075688772f;
              const float* rh = &rh_blk[(size_t)(ch*64 + jp)*3];
              aY[0]=f2bfs(SQ3*rh[0]);
              aY[1]=f2bfs(SQ3*rh[1]);
              aY[2]=f2bfs(SQ3*rh[2]);
            }
            #pragma unroll
            for (int nt=0;nt<2;nt++)
              dotC[nt] = __builtin_amdgcn_mfma_f32_16x16x32_bf16(aY, vBf[nt], zf, 0,0,0);
          }

          #pragma unroll
          for (int nt=0;nt<2;nt++){
            f32x4 c2 = zf;
            #pragma unroll
            for (int ks=0;ks<4;ks++)
              c2 = __builtin_amdgcn_mfma_f32_16x16x32_bf16(af[ks], w2f[nt][ks], c2, 0,0,0);
            const int dd = dbase+nt*16+cc;
            float gg[4];
            if (p<3){
              // C row q*4+r of tile (g,mm) <-> j = ch*64 + g*32 + q*8 + mm*4 + r
              const float* hp = hb + (size_t)(ch*64 + g*32 + q*8 + mm*4)*Dd + dd;
              #pragma unroll
              for (int r=0;r<4;r++)
                gg[r] = (c2[r]+b2v[nt]) * hp[(size_t)r*Dd];
            } else {
              #pragma unroll
              for (int r=0;r<4;r++)
                gg[r] = (c2[r]+b2v[nt]) * dotC[nt][r];
            }
            bB[nt][mm*2+0] = cvtpk(gg[0], gg[1]);
            bB[nt][mm*2+1] = cvtpk(gg[2], gg[3]);
          }
        }
        // ---- j-reduction MFMA over this 32-j group (B-frag from registers) ----
        bf16x8 aR = *(const bf16x8*)(ytrow + ch*64 + g*32 + q*8);
        u32* arp = (u32*)&aR;
        arp[0]&=gmask; arp[1]&=gmask; arp[2]&=gmask; arp[3]&=gmask;
        #pragma unroll
        for (int nt=0;nt<2;nt++){
          u32x4 bw = { bB[nt][0], bB[nt][1], bB[nt][2], bB[nt][3] };
          bf16x8 bG = __builtin_bit_cast(bf16x8, bw);
          accred[nt] = __builtin_amdgcn_mfma_f32_16x16x32_bf16(aR, bG, accred[nt], 0,0,0);
        }
      }
    }
  }

  __syncthreads();                     // all s_hid reads done: safe to alias

  // ---- scatter accred rows -> outputs / LN inputs (complete per wave) ----
  #pragma unroll
  for (int nt=0;nt<2;nt++){
    const int d = dbase + nt*16 + cc;
    #pragma unroll
    for (int r=0;r<4;r++){
      const int rw = q*4 + r;
      float val = accred[nt][r];
      if (rw==0)      s_msg[d] = val;
      else if (rw<=3) out_v[(size_t)bi*3*Dd + (size_t)(rw-1)*Dd + d] = val*v_scale[d];
      else if (rw<=8) out_t[(size_t)bi*5*Dd + (size_t)(rw-4)*Dd + d] = val*t_scale[d];
      else if (rw==9) s_xn[d] = val;
    }
  }
  __syncthreads();

  // ---- LayerNorm stats (wave 0) ----
  if (tid < 64){
    float a0=s_msg[tid]+s_xn[tid], a1=s_msg[tid+64]+s_xn[tid+64];
    float s1=a0+a1, s2=a0*a0+a1*a1;
    #pragma unroll
    for (int off=1;off<64;off<<=1){
      s1 += __shfl_xor(s1,off);
      s2 += __shfl_xor(s2,off);
    }
    if (tid==0){
      float m   = s1*(1.f/Dd);
      float var = fmaxf(s2*(1.f/Dd) - m*m, 0.f);
      s_mv[0]=m;
      s_mv[1]=rsqrtf(var+1e-5f);
    }
  }
  __syncthreads();
  if (tid < Dd){
    float msg = s_msg[tid]+s_xn[tid];
    s_xn[tid] = (msg - s_mv[0])*s_mv[1]*ln_g[tid] + ln_b[tid];
  }
  __syncthreads();

  // ---- delta_s = xn @ out_w + out_b (2 k-segments across 256 threads) ----
  {
    int dp = tid & 127, seg = tid >> 7;
    float pa = 0.f;
    #pragma unroll 8
    for (int k=seg*64;k<seg*64+64;k++)
      pa += s_xn[k]*out_w[k*Dd+dp];
    s_part[seg*Dd+dp]=pa;
  }
  __syncthreads();
  if (tid < Dd)
    out_s[(size_t)bi*Dd+tid] = s_part[tid]+s_part[Dd+tid]+out_b[tid];
}

extern "C" void kernel_launch(void* const* d_in, const int* in_sizes, int n_in,
                              void* d_out, int out_size, void* d_ws, size_t ws_size,
                              hipStream_t stream) {
  const float* node_s = (const float*)d_in[0];
  const float* node_v = (const float*)d_in[1];
  // d_in[2] = node_t (unused by reference)
  const float* rbf    = (const float*)d_in[3];
  const float* r_hat  = (const float*)d_in[4];
  const float* maskp  = (const float*)d_in[5];
  const float* r0w1=(const float*)d_in[6],  *r0b1=(const float*)d_in[7];
  const float* r0w2=(const float*)d_in[8],  *r0b2=(const float*)d_in[9];
  const float* r1w1=(const float*)d_in[10], *r1b1=(const float*)d_in[11];
  const float* r1w2=(const float*)d_in[12], *r1b2=(const float*)d_in[13];
  const float* r2w1=(const float*)d_in[14], *r2b1=(const float*)d_in[15];
  const float* r2w2=(const float*)d_in[16], *r2b2=(const float*)d_in[17];
  const float* r3w1=(const float*)d_in[18], *r3b1=(const float*)d_in[19];
  const float* r3w2=(const float*)d_in[20], *r3b2=(const float*)d_in[21];
  const float* src_w  =(const float*)d_in[22];
  const float* ln_g   =(const float*)d_in[23];
  const float* ln_b   =(const float*)d_in[24];
  const float* out_w  =(const float*)d_in[25];
  const float* out_b  =(const float*)d_in[26];
  const float* v_scale=(const float*)d_in[27];
  const float* t_scale=(const float*)d_in[28];

  float* h_ws = (float*)d_ws;                    // 512*128 f32 = 256 KiB
  float* out_s = (float*)d_out;
  float* out_v = out_s + (size_t)Bb*Nn*Dd;
  float* out_t = out_v + (size_t)Bb*Nn*3*Dd;

  prep_kernel<<<dim3(Bb*Nn + 32), dim3(128), 0, stream>>>(
      node_s, src_w,
      r0w1, r1w1, r2w1, r3w1, r0w2, r1w2, r2w2, r3w2,
      h_ws);
  se3_mfma10<<<dim3(Bb*Nn), dim3(256), 0, stream>>>(
      node_v, rbf, r_hat, maskp,
      r0b1,r0b2, r1b1,r1b2, r2b1,r2b2, r3b1,r3b2,
      ln_g, ln_b, out_w, out_b, v_scale, t_scale,
      h_ws, out_s, out_v, out_t);
}

// Round 7
// 203.339 us; speedup vs baseline: 1.0441x; 1.0441x over previous
//
#include <hip/hip_runtime.h>

#define Bb 2
#define Nn 256
#define Dd 128
#define Rr 32

typedef unsigned short u16;
typedef unsigned int   u32;
typedef __attribute__((ext_vector_type(8))) short bf16x8;
typedef __attribute__((ext_vector_type(4))) short bf16x4;
typedef __attribute__((ext_vector_type(4))) float f32x4;
typedef __attribute__((ext_vector_type(2))) u32   u32x2;
typedef __attribute__((ext_vector_type(4))) u32   u32x4;

// one-time bf16-transposed radial weights (fragment-order), filled by prep_kernel
__device__ u16 g_w1t[4*Dd*Rr];   // per p: W1T[dd*32 + kk] = bf16(W1[kk][dd])
__device__ u16 g_w2t[4*Dd*Dd];   // per p: W2T[dd*128 + kk] = bf16(W2[kk][dd])

__device__ __forceinline__ short f2bfs(float f){
  u32 u = __float_as_uint(f);
  u += 0x7FFFu + ((u >> 16) & 1u);   // RNE
  return (short)(u >> 16);
}
__device__ __forceinline__ u16 f2bf(float f){
  u32 u = __float_as_uint(f);
  u += 0x7FFFu + ((u >> 16) & 1u);
  return (u16)(u >> 16);
}
// packed f32x2 -> bf16x2 (RNE), one VALU op
__device__ __forceinline__ u32 cvtpk(float a, float b){
  u32 r;
  asm("v_cvt_pk_bf16_f32 %0, %1, %2" : "=v"(r) : "v"(a), "v"(b));
  return r;
}
// 3-bit LDS chunk swizzle for s_hid: spreads row bits 0..3 into bank bits
__device__ __forceinline__ int swz(int j){
  return (j&3) | ((((j>>2)^(j>>3))&1)<<2);
}

// ---- prep: blocks [0,512): h = node_s @ src_w ; blocks [512,544): weight bf16-transpose
__global__ __launch_bounds__(128) void prep_kernel(
    const float* __restrict__ node_s, const float* __restrict__ src_w,
    const float* __restrict__ r0w1, const float* __restrict__ r1w1,
    const float* __restrict__ r2w1, const float* __restrict__ r3w1,
    const float* __restrict__ r0w2, const float* __restrict__ r1w2,
    const float* __restrict__ r2w2, const float* __restrict__ r3w2,
    float* __restrict__ h_out)
{
  const int bx = blockIdx.x;
  const int t  = threadIdx.x;
  if (bx < Bb*Nn){
    __shared__ float s_row[Dd];
    s_row[t] = node_s[(size_t)bx*Dd + t];
    __syncthreads();
    float acc = 0.f;
    #pragma unroll 8
    for (int k=0;k<Dd;k++) acc += s_row[k]*src_w[k*Dd + t];
    h_out[(size_t)bx*Dd + t] = acc;
  } else {
    const int kb = bx - Bb*Nn;          // 0..31
    const int p  = kb >> 3, sl = kb & 7;
    const float* W1 = (p==0)?r0w1:(p==1)?r1w1:(p==2)?r2w1:r3w1;
    const float* W2 = (p==0)?r0w2:(p==1)?r1w2:(p==2)?r2w2:r3w2;
    u16* W1T = g_w1t + p*Dd*Rr;
    u16* W2T = g_w2t + p*Dd*Dd;
    // coalesced reads (linear in), scattered writes (stores don't stall)
    #pragma unroll
    for (int it=0; it<4; it++){
      int in = sl*512 + it*128 + t;                  // in = kk*Dd + dd
      W1T[(in & 127)*Rr + (in >> 7)] = f2bf(W1[in]);
    }
    #pragma unroll
    for (int it=0; it<16; it++){
      int in = sl*2048 + it*128 + t;                 // in = kk*Dd + dd
      W2T[(in & 127)*Dd + (in >> 7)] = f2bf(W2[in]);
    }
  }
}

// ---- main: 8 waves/block. Wave (mpair=w&1, dgrp=w>>1): d-cols [dgrp*32,+32),
// j-half mpair. Per chunk (64 j): GEMM1^T -> SiLU -> s_hid (double-buffered,
// XOR-swizzled) -> barrier -> GEMM2 with PERMUTED m-tile rows (tile m holds
// j = q*8+m*4+r) so each lane's post-epilogue G values form its j-reduction
// B-fragment directly in registers (no s_G LDS round-trip). One barrier/chunk.
// launch_bounds (512,2): 256-reg/wave budget -- the (512,4) variants capped at
// 128 total (64 arch VGPR + acc) and spilled to scratch (WRITE_SIZE 7-24MB).
__global__ __launch_bounds__(512,2) void se3_mfma11(
    const float* __restrict__ node_v,
    const float* __restrict__ rbf,
    const float* __restrict__ r_hat,
    const float* __restrict__ maskp,
    const float* __restrict__ r0b1, const float* __restrict__ r0b2,
    const float* __restrict__ r1b1, const float* __restrict__ r1b2,
    const float* __restrict__ r2b1, const float* __restrict__ r2b2,
    const float* __restrict__ r3b1, const float* __restrict__ r3b2,
    const float* __restrict__ ln_g, const float* __restrict__ ln_b,
    const float* __restrict__ out_w, const float* __restrict__ out_b,
    const float* __restrict__ v_scale, const float* __restrict__ t_scale,
    const float* __restrict__ h_ws,
    float* __restrict__ out_s, float* __restrict__ out_v, float* __restrict__ out_t)
{
  __shared__ u16   s_rbf[Nn*36];       // 18432: rbf bf16, row stride 36
  __shared__ u16   s_hid[2*64*128];    // 32768: double-buffered, swizzled
  __shared__ u16   s_YT[10*264];       //  5280
  __shared__ u16   s_Y1r[3*264];       //  1584
  __shared__ float s_red[16*130];      //  8320: wave-pair partial merge
  __shared__ float s_msg[Dd];          //   512
  __shared__ float s_xn[Dd];           //   512
  __shared__ float s_part[4*Dd];       //  2048
  __shared__ float s_mv[2];            //     8  -> total 69464 B (2 blocks/CU)

  const int tid  = threadIdx.x;
  const int bi   = blockIdx.x;            // b*N + i
  const int b    = bi >> 8;
  const int lane = tid & 63;
  const int w    = tid >> 6;              // wave 0..7
  const int q    = lane >> 4;
  const int cc   = lane & 15;
  const int mpair= w & 1;                 // j-half owner
  const int dgrp = w >> 1;                // 0..3
  const int dbase= dgrp*32;

  // ---- setup: stacked-Y rows (mask folded), raw Y1 ----
  if (tid < Nn){
    int j = tid;
    size_t pidx = (size_t)bi*Nn + j;
    float mk = maskp[pidx];
    float x = r_hat[pidx*3+0];
    float y = r_hat[pidx*3+1];
    float z = r_hat[pidx*3+2];
    const float SQ3=1.7320508075688772f;
    const float C15=3.8729833462074170f;
    const float C5H=1.1180339887498949f;
    float y1a=SQ3*x, y1b=SQ3*y, y1c=SQ3*z;
    s_YT[0*264+j]=f2bf(mk);
    s_YT[1*264+j]=f2bf(y1a*mk);
    s_YT[2*264+j]=f2bf(y1b*mk);
    s_YT[3*264+j]=f2bf(y1c*mk);
    s_YT[4*264+j]=f2bf(C15*x*y*mk);
    s_YT[5*264+j]=f2bf(C15*y*z*mk);
    s_YT[6*264+j]=f2bf(C5H*(3.f*z*z-1.f)*mk);
    s_YT[7*264+j]=f2bf(C15*x*z*mk);
    s_YT[8*264+j]=f2bf(0.5f*C15*(x*x-y*y)*mk);
    s_YT[9*264+j]=f2bf(mk);
    s_Y1r[0*264+j]=f2bf(y1a);
    s_Y1r[1*264+j]=f2bf(y1b);
    s_Y1r[2*264+j]=f2bf(y1c);
  }

  const float* rbf_blk = rbf + (size_t)bi*Nn*Rr;
  const float* hb      = h_ws + (size_t)b*Nn*Dd;

  // ---- stage rbf as bf16 (row stride 36): packed pairs ----
  for (int idx=tid; idx<Nn*Rr/2; idx+=512){
    int j = idx >> 4, r2 = (idx & 15)*2;
    const float* src = &rbf_blk[j*Rr + r2];
    float v0 = src[0], v1 = src[1];
    *(u32*)&s_rbf[j*36 + r2] = cvtpk(v0, v1);
  }

  // ---- node_v B-fragments for the dot MFMA ----
  bf16x8 vBf[2];
  {
    const float* nv = node_v + (size_t)bi*3*Dd;
    #pragma unroll
    for (int nt=0;nt<2;nt++){
      int dd = dbase+nt*16+cc;
      bf16x8 t = {0,0,0,0,0,0,0,0};
      if (q==0){
        t[0]=f2bfs(nv[0*Dd+dd]);
        t[1]=f2bfs(nv[1*Dd+dd]);
        t[2]=f2bfs(nv[2*Dd+dd]);
      }
      vBf[nt]=t;
    }
  }

  __syncthreads();                       // setup + staging visible

  const f32x4 zf = {0.f,0.f,0.f,0.f};
  f32x4 accred[2] = {zf, zf};
  int buf = 0;

  #pragma unroll 1
  for (int p=0;p<4;p++){
    const float* B1p = (p==0)?r0b1:(p==1)?r1b1:(p==2)?r2b1:r3b1;
    const float* B2p = (p==0)?r0b2:(p==1)?r1b2:(p==2)?r2b2:r3b2;
    const u16* W1T = g_w1t + p*Dd*Rr;
    const u16* W2T = g_w2t + p*Dd*Dd;
    const int lo = (p==0)?0:(p==1)?1:(p==2)?4:9;
    const int hi = (p==0)?0:(p==1)?3:(p==2)?8:9;
    const u32 gmask = (cc>=lo && cc<=hi) ? 0xFFFFFFFFu : 0u;
    const u16* ytrow = &s_YT[(cc<10?cc:9)*264];

    // per-p weight fragments (vector loads from prepped layout)
    bf16x8 w1f[2];
    bf16x8 w2f[2][4];
    f32x4  b1v4[2];
    float  b2v[2];
    #pragma unroll
    for (int nt=0;nt<2;nt++){
      int dd = dbase+nt*16+cc;
      b1v4[nt] = *(const f32x4*)&B1p[dbase + nt*16 + q*4];
      b2v[nt]=B2p[dd];
      w1f[nt] = *(const bf16x8*)&W1T[dd*Rr + q*8];
      #pragma unroll
      for (int ks=0;ks<4;ks++)
        w2f[nt][ks] = *(const bf16x8*)&W2T[dd*Dd + ks*32 + q*8];
    }

    #pragma unroll 1
    for (int ch=0; ch<4; ch++){
      // ---- GEMM1^T: A = w1f (rows d), B = rbf frag (cols j) -> s_hid[buf] ----
      #pragma unroll
      for (int jt=0;jt<2;jt++){
        const int jrow = (mpair*2+jt)*16 + cc;       // j within chunk
        const u16* bp = &s_rbf[(ch*64 + jrow)*36 + q*8];
        bf16x4 lo4 = *(const bf16x4*)bp;
        bf16x4 hi4 = *(const bf16x4*)(bp+4);
        bf16x8 rbff = {lo4[0],lo4[1],lo4[2],lo4[3],hi4[0],hi4[1],hi4[2],hi4[3]};
        #pragma unroll
        for (int nt=0;nt<2;nt++){
          f32x4 hc = __builtin_amdgcn_mfma_f32_16x16x32_bf16(w1f[nt], rbff, zf, 0,0,0);
          float s[4];
          #pragma unroll
          for (int r=0;r<4;r++){
            float x  = hc[r] + b1v4[nt][r];
            float e  = __expf(-x);
            s[r]     = x*__builtin_amdgcn_rcpf(1.f+e);
          }
          u32x2 pk = { cvtpk(s[0], s[1]), cvtpk(s[2], s[3]) };
          const int c0 = dgrp*4 + nt*2 + (q>>1);     // d-chunk index
          *(u32x2*)&s_hid[buf*8192 + jrow*128 + ((c0 ^ swz(jrow))<<3) + (q&1)*4] = pk;
        }
      }
      __syncthreads();                   // hidden[buf] ready (only barrier/chunk)

      // ---- GEMM2 (permuted m-tiles) + epilogue -> in-register B-frags ----
      u32 bB[2][4];
      #pragma unroll
      for (int mm=0;mm<2;mm++){
        // permuted A-row: tile mm row cc <-> j-local = (cc>>2)*8 + mm*4 + (cc&3)
        const int jp = mpair*32 + ((cc>>2)<<3) + mm*4 + (cc&3);
        bf16x8 af[4];
        #pragma unroll
        for (int ks=0;ks<4;ks++)
          af[ks] = *(const bf16x8*)&s_hid[buf*8192 + jp*128 + (((ks*4+q) ^ swz(jp))<<3)];

        f32x4 dotC[2];
        if (p==3){                       // dot(v, Y1): A rows follow same perm
          bf16x8 aY = {0,0,0,0,0,0,0,0};
          if (q==0){
            int jg = ch*64 + jp;
            aY[0]=(short)s_Y1r[0*264+jg];
            aY[1]=(short)s_Y1r[1*264+jg];
            aY[2]=(short)s_Y1r[2*264+jg];
          }
          #pragma unroll
          for (int nt=0;nt<2;nt++)
            dotC[nt] = __builtin_amdgcn_mfma_f32_16x16x32_bf16(aY, vBf[nt], zf, 0,0,0);
        }

        #pragma unroll
        for (int nt=0;nt<2;nt++){
          f32x4 c2 = zf;
          #pragma unroll
          for (int ks=0;ks<4;ks++)
            c2 = __builtin_amdgcn_mfma_f32_16x16x32_bf16(af[ks], w2f[nt][ks], c2, 0,0,0);
          const int dd = dbase+nt*16+cc;
          float g[4];
          if (p<3){
            // C row q*4+r of tile mm <-> j = ch*64 + mpair*32 + q*8 + mm*4 + r
            const float* hp = hb + (size_t)(ch*64 + mpair*32 + q*8 + mm*4)*Dd + dd;
            #pragma unroll
            for (int r=0;r<4;r++)
              g[r] = (c2[r]+b2v[nt]) * hp[(size_t)r*Dd];
          } else {
            #pragma unroll
            for (int r=0;r<4;r++)
              g[r] = (c2[r]+b2v[nt]) * dotC[nt][r];
          }
          // lane's j-red B-frag slots: k = q*8 + mm*4 + r
          bB[nt][mm*2+0] = cvtpk(g[0], g[1]);
          bB[nt][mm*2+1] = cvtpk(g[2], g[3]);
        }
      }

      // ---- j-reduction MFMA: B-frag straight from registers ----
      {
        bf16x8 aR = *(const bf16x8*)(ytrow + ch*64 + mpair*32 + q*8);
        u32* arp = (u32*)&aR;
        arp[0]&=gmask; arp[1]&=gmask; arp[2]&=gmask; arp[3]&=gmask;
        #pragma unroll
        for (int nt=0;nt<2;nt++){
          u32x4 bw = { bB[nt][0], bB[nt][1], bB[nt][2], bB[nt][3] };
          bf16x8 bG = __builtin_bit_cast(bf16x8, bw);
          accred[nt] = __builtin_amdgcn_mfma_f32_16x16x32_bf16(aR, bG, accred[nt], 0,0,0);
        }
      }
      buf ^= 1;
    }
  }

  // ---- merge wave-pair partials, then scatter ----
  if (mpair){
    #pragma unroll
    for (int nt=0;nt<2;nt++){
      const int d = dbase + nt*16 + cc;
      #pragma unroll
      for (int r=0;r<4;r++)
        s_red[(q*4+r)*130 + d] = accred[nt][r];
    }
  }
  __syncthreads();
  if (!mpair){
    #pragma unroll
    for (int nt=0;nt<2;nt++){
      const int d = dbase + nt*16 + cc;
      #pragma unroll
      for (int r=0;r<4;r++){
        const int rw = q*4 + r;
        float val = accred[nt][r] + s_red[rw*130 + d];
        if (rw==0)      s_msg[d] = val;
        else if (rw<=3) out_v[(size_t)bi*3*Dd + (size_t)(rw-1)*Dd + d] = val*v_scale[d];
        else if (rw<=8) out_t[(size_t)bi*5*Dd + (size_t)(rw-4)*Dd + d] = val*t_scale[d];
        else if (rw==9) s_xn[d] = val;
      }
    }
  }
  __syncthreads();

  // ---- LayerNorm stats (wave 0) ----
  if (tid < 64){
    float a0=s_msg[tid]+s_xn[tid], a1=s_msg[tid+64]+s_xn[tid+64];
    float s1=a0+a1, s2=a0*a0+a1*a1;
    #pragma unroll
    for (int off=1;off<64;off<<=1){
      s1 += __shfl_xor(s1,off);
      s2 += __shfl_xor(s2,off);
    }
    if (tid==0){
      float m   = s1*(1.f/Dd);
      float var = fmaxf(s2*(1.f/Dd) - m*m, 0.f);
      s_mv[0]=m;
      s_mv[1]=rsqrtf(var+1e-5f);
    }
  }
  __syncthreads();
  if (tid < Dd){
    float msg = s_msg[tid]+s_xn[tid];
    s_xn[tid] = (msg - s_mv[0])*s_mv[1]*ln_g[tid] + ln_b[tid];
  }
  __syncthreads();

  // ---- delta_s = xn @ out_w + out_b (4 k-segments across 512 threads) ----
  {
    int dp = tid & 127, seg = tid >> 7;
    float pa = 0.f;
    #pragma unroll 8
    for (int k=seg*32;k<seg*32+32;k++)
      pa += s_xn[k]*out_w[k*Dd+dp];
    s_part[seg*Dd+dp]=pa;
  }
  __syncthreads();
  if (tid < Dd)
    out_s[(size_t)bi*Dd+tid] = s_part[tid]+s_part[Dd+tid]+s_part[2*Dd+tid]+s_part[3*Dd+tid]+out_b[tid];
}

extern "C" void kernel_launch(void* const* d_in, const int* in_sizes, int n_in,
                              void* d_out, int out_size, void* d_ws, size_t ws_size,
                              hipStream_t stream) {
  const float* node_s = (const float*)d_in[0];
  const float* node_v = (const float*)d_in[1];
  // d_in[2] = node_t (unused by reference)
  const float* rbf    = (const float*)d_in[3];
  const float* r_hat  = (const float*)d_in[4];
  const float* maskp  = (const float*)d_in[5];
  const float* r0w1=(const float*)d_in[6],  *r0b1=(const float*)d_in[7];
  const float* r0w2=(const float*)d_in[8],  *r0b2=(const float*)d_in[9];
  const float* r1w1=(const float*)d_in[10], *r1b1=(const float*)d_in[11];
  const float* r1w2=(const float*)d_in[12], *r1b2=(const float*)d_in[13];
  const float* r2w1=(const float*)d_in[14], *r2b1=(const float*)d_in[15];
  const float* r2w2=(const float*)d_in[16], *r2b2=(const float*)d_in[17];
  const float* r3w1=(const float*)d_in[18], *r3b1=(const float*)d_in[19];
  const float* r3w2=(const float*)d_in[20], *r3b2=(const float*)d_in[21];
  const float* src_w  =(const float*)d_in[22];
  const float* ln_g   =(const float*)d_in[23];
  const float* ln_b   =(const float*)d_in[24];
  const float* out_w  =(const float*)d_in[25];
  const float* out_b  =(const float*)d_in[26];
  const float* v_scale=(const float*)d_in[27];
  const float* t_scale=(const float*)d_in[28];

  float* h_ws = (float*)d_ws;                    // 512*128 f32 = 256 KiB
  float* out_s = (float*)d_out;
  float* out_v = out_s + (size_t)Bb*Nn*Dd;
  float* out_t = out_v + (size_t)Bb*Nn*3*Dd;

  prep_kernel<<<dim3(Bb*Nn + 32), dim3(128), 0, stream>>>(
      node_s, src_w,
      r0w1, r1w1, r2w1, r3w1, r0w2, r1w2, r2w2, r3w2,
      h_ws);
  se3_mfma11<<<dim3(Bb*Nn), dim3(512), 0, stream>>>(
      node_v, rbf, r_hat, maskp,
      r0b1,r0b2, r1b1,r1b2, r2b1,r2b2, r3b1,r3b2,
      ln_g, ln_b, out_w, out_b, v_scale, t_scale,
      h_ws, out_s, out_v, out_t);
}

// Round 8
// 187.862 us; speedup vs baseline: 1.1301x; 1.0824x over previous
//
#include <hip/hip_runtime.h>

#define Bb 2
#define Nn 256
#define Dd 128
#define Rr 32

typedef unsigned short u16;
typedef unsigned int   u32;
typedef __attribute__((ext_vector_type(8))) short bf16x8;
typedef __attribute__((ext_vector_type(4))) short bf16x4;
typedef __attribute__((ext_vector_type(4))) float f32x4;
typedef __attribute__((ext_vector_type(2))) u32   u32x2;
typedef __attribute__((ext_vector_type(4))) u32   u32x4;

// one-time bf16-transposed radial weights (fragment-order), filled by prep_kernel
__device__ u16 g_w1t[4*Dd*Rr];   // per p: W1T[dd*32 + kk] = bf16(W1[kk][dd])
__device__ u16 g_w2t[4*Dd*Dd];   // per p: W2T[dd*128 + kk] = bf16(W2[kk][dd])

__device__ __forceinline__ short f2bfs(float f){
  u32 u = __float_as_uint(f);
  u += 0x7FFFu + ((u >> 16) & 1u);   // RNE
  return (short)(u >> 16);
}
__device__ __forceinline__ u16 f2bf(float f){
  u32 u = __float_as_uint(f);
  u += 0x7FFFu + ((u >> 16) & 1u);
  return (u16)(u >> 16);
}
// packed f32x2 -> bf16x2 (RNE), one VALU op
__device__ __forceinline__ u32 cvtpk(float a, float b){
  u32 r;
  asm("v_cvt_pk_bf16_f32 %0, %1, %2" : "=v"(r) : "v"(a), "v"(b));
  return r;
}
// 3-bit LDS granule swizzle for s_hid rows (16B granules, 16 per row)
__device__ __forceinline__ int swz(int j){
  return (j&3) | ((((j>>2)^(j>>3))&1)<<2);
}

// ---- prep: blocks [0,512): h = node_s @ src_w ; blocks [512,544): weight bf16-transpose
__global__ __launch_bounds__(128) void prep_kernel(
    const float* __restrict__ node_s, const float* __restrict__ src_w,
    const float* __restrict__ r0w1, const float* __restrict__ r1w1,
    const float* __restrict__ r2w1, const float* __restrict__ r3w1,
    const float* __restrict__ r0w2, const float* __restrict__ r1w2,
    const float* __restrict__ r2w2, const float* __restrict__ r3w2,
    float* __restrict__ h_out)
{
  const int bx = blockIdx.x;
  const int t  = threadIdx.x;
  if (bx < Bb*Nn){
    __shared__ float s_row[Dd];
    s_row[t] = node_s[(size_t)bx*Dd + t];
    __syncthreads();
    float acc = 0.f;
    #pragma unroll 8
    for (int k=0;k<Dd;k++) acc += s_row[k]*src_w[k*Dd + t];
    h_out[(size_t)bx*Dd + t] = acc;
  } else {
    const int kb = bx - Bb*Nn;          // 0..31
    const int p  = kb >> 3, sl = kb & 7;
    const float* W1 = (p==0)?r0w1:(p==1)?r1w1:(p==2)?r2w1:r3w1;
    const float* W2 = (p==0)?r0w2:(p==1)?r1w2:(p==2)?r2w2:r3w2;
    u16* W1T = g_w1t + p*Dd*Rr;
    u16* W2T = g_w2t + p*Dd*Dd;
    // coalesced reads (linear in), scattered writes (stores don't stall)
    #pragma unroll
    for (int it=0; it<4; it++){
      int in = sl*512 + it*128 + t;                  // in = kk*Dd + dd
      W1T[(in & 127)*Rr + (in >> 7)] = f2bf(W1[in]);
    }
    #pragma unroll
    for (int it=0; it<16; it++){
      int in = sl*2048 + it*128 + t;                 // in = kk*Dd + dd
      W2T[(in & 127)*Dd + (in >> 7)] = f2bf(W2[in]);
    }
  }
}

// ---- main: 8 waves/block, 512 thr. Wave w owns d-cols [w*16,+16) and ALL j:
// per-wave register state halves vs the 32-d variants (w2f 16, w1f 4, accred 4)
// so the live set fits the 128-reg/wave budget of (512,4) with NO scratch spill
// (the 32-d variants either spilled 7-24MB at (512,4) or dropped to 1 block/CU
// at (512,2)). accred is complete per wave -> no s_red pair-merge. Per chunk:
// GEMM1^T -> SiLU -> s_hid (dbuf, swizzled) -> barrier -> GEMM2 (4 permuted
// m-tiles: tile (g,mm) row x holds j = g*32+(x>>2)*8+mm*4+(x&3)) -> epilogue
// values land as the j-reduction B-fragment in registers.
__global__ __launch_bounds__(512,4) void se3_mfma12(
    const float* __restrict__ node_v,
    const float* __restrict__ rbf,
    const float* __restrict__ r_hat,
    const float* __restrict__ maskp,
    const float* __restrict__ r0b1, const float* __restrict__ r0b2,
    const float* __restrict__ r1b1, const float* __restrict__ r1b2,
    const float* __restrict__ r2b1, const float* __restrict__ r2b2,
    const float* __restrict__ r3b1, const float* __restrict__ r3b2,
    const float* __restrict__ ln_g, const float* __restrict__ ln_b,
    const float* __restrict__ out_w, const float* __restrict__ out_b,
    const float* __restrict__ v_scale, const float* __restrict__ t_scale,
    const float* __restrict__ h_ws,
    float* __restrict__ out_s, float* __restrict__ out_v, float* __restrict__ out_t)
{
  __shared__ u16   s_rbf[Nn*36];       // 18432: rbf bf16, row stride 36
  __shared__ u16   s_hid[2*64*128];    // 32768: double-buffered, swizzled
  __shared__ u16   s_YT[10*264];       //  5280
  __shared__ u16   s_Y1r[3*264];       //  1584
  __shared__ float s_msg[Dd];          //   512
  __shared__ float s_xn[Dd];           //   512
  __shared__ float s_part[4*Dd];       //  2048
  __shared__ float s_mv[2];            //     8  -> total 61144 B (2 blocks/CU)

  const int tid  = threadIdx.x;
  const int bi   = blockIdx.x;            // b*N + i
  const int b    = bi >> 8;
  const int lane = tid & 63;
  const int w    = tid >> 6;              // wave 0..7
  const int q    = lane >> 4;
  const int cc   = lane & 15;
  const int dwb  = w*16;                  // this wave's 16-col d-base

  // ---- setup: stacked-Y rows (mask folded), raw Y1 ----
  if (tid < Nn){
    int j = tid;
    size_t pidx = (size_t)bi*Nn + j;
    float mk = maskp[pidx];
    float x = r_hat[pidx*3+0];
    float y = r_hat[pidx*3+1];
    float z = r_hat[pidx*3+2];
    const float SQ3=1.7320508075688772f;
    const float C15=3.8729833462074170f;
    const float C5H=1.1180339887498949f;
    float y1a=SQ3*x, y1b=SQ3*y, y1c=SQ3*z;
    s_YT[0*264+j]=f2bf(mk);
    s_YT[1*264+j]=f2bf(y1a*mk);
    s_YT[2*264+j]=f2bf(y1b*mk);
    s_YT[3*264+j]=f2bf(y1c*mk);
    s_YT[4*264+j]=f2bf(C15*x*y*mk);
    s_YT[5*264+j]=f2bf(C15*y*z*mk);
    s_YT[6*264+j]=f2bf(C5H*(3.f*z*z-1.f)*mk);
    s_YT[7*264+j]=f2bf(C15*x*z*mk);
    s_YT[8*264+j]=f2bf(0.5f*C15*(x*x-y*y)*mk);
    s_YT[9*264+j]=f2bf(mk);
    s_Y1r[0*264+j]=f2bf(y1a);
    s_Y1r[1*264+j]=f2bf(y1b);
    s_Y1r[2*264+j]=f2bf(y1c);
  }

  const float* rbf_blk = rbf + (size_t)bi*Nn*Rr;
  const float* hb      = h_ws + (size_t)b*Nn*Dd;

  // ---- stage rbf as bf16 (row stride 36): packed pairs ----
  for (int idx=tid; idx<Nn*Rr/2; idx+=512){
    int j = idx >> 4, r2 = (idx & 15)*2;
    const float* src = &rbf_blk[j*Rr + r2];
    float v0 = src[0], v1 = src[1];
    *(u32*)&s_rbf[j*36 + r2] = cvtpk(v0, v1);
  }

  // ---- node_v B-fragment for the dot MFMA (wave's 16 d-cols) ----
  bf16x8 vBf;
  {
    const float* nv = node_v + (size_t)bi*3*Dd;
    int dd = dwb+cc;
    bf16x8 t = {0,0,0,0,0,0,0,0};
    if (q==0){
      t[0]=f2bfs(nv[0*Dd+dd]);
      t[1]=f2bfs(nv[1*Dd+dd]);
      t[2]=f2bfs(nv[2*Dd+dd]);
    }
    vBf=t;
  }

  __syncthreads();                       // setup + staging visible

  const f32x4 zf = {0.f,0.f,0.f,0.f};
  f32x4 accred = zf;
  int buf = 0;

  #pragma unroll 1
  for (int p=0;p<4;p++){
    const float* B1p = (p==0)?r0b1:(p==1)?r1b1:(p==2)?r2b1:r3b1;
    const float* B2p = (p==0)?r0b2:(p==1)?r1b2:(p==2)?r2b2:r3b2;
    const u16* W1T = g_w1t + p*Dd*Rr;
    const u16* W2T = g_w2t + p*Dd*Dd;
    const int lo = (p==0)?0:(p==1)?1:(p==2)?4:9;
    const int hi = (p==0)?0:(p==1)?3:(p==2)?8:9;
    const u32 gmask = (cc>=lo && cc<=hi) ? 0xFFFFFFFFu : 0u;
    const u16* ytrow = &s_YT[(cc<10?cc:9)*264];

    // per-p weight fragments for this wave's 16 d-cols
    bf16x8 w1f  = *(const bf16x8*)&W1T[(dwb+cc)*Rr + q*8];
    bf16x8 w2f[4];
    #pragma unroll
    for (int ks=0;ks<4;ks++)
      w2f[ks] = *(const bf16x8*)&W2T[(dwb+cc)*Dd + ks*32 + q*8];
    f32x4 b1v4 = *(const f32x4*)&B1p[dwb + q*4];
    float b2v  = B2p[dwb + cc];

    #pragma unroll 1
    for (int ch=0; ch<4; ch++){
      // ---- GEMM1^T: A = w1f (rows = wave's 16 d), B = rbf (cols j); 4 j-tiles ----
      #pragma unroll 1
      for (int jt=0;jt<4;jt++){
        const int jrow = jt*16 + cc;                 // j within chunk
        const u16* bp = &s_rbf[(ch*64 + jrow)*36 + q*8];
        bf16x4 lo4 = *(const bf16x4*)bp;
        bf16x4 hi4 = *(const bf16x4*)(bp+4);
        bf16x8 rbff = {lo4[0],lo4[1],lo4[2],lo4[3],hi4[0],hi4[1],hi4[2],hi4[3]};
        f32x4 hc = __builtin_amdgcn_mfma_f32_16x16x32_bf16(w1f, rbff, zf, 0,0,0);
        float s[4];
        #pragma unroll
        for (int r=0;r<4;r++){
          float x  = hc[r] + b1v4[r];
          float e  = __expf(-x);
          s[r]     = x*__builtin_amdgcn_rcpf(1.f+e);
        }
        u32x2 pk = { cvtpk(s[0], s[1]), cvtpk(s[2], s[3]) };
        const int c0 = w*2 + (q>>1);                 // 16B d-granule 0..15
        *(u32x2*)&s_hid[buf*8192 + jrow*128 + ((c0 ^ swz(jrow))<<3) + (q&1)*4] = pk;
      }
      __syncthreads();                   // hidden[buf] ready (only barrier/chunk)

      // ---- GEMM2 over 4 permuted tiles + epilogue -> in-register B-frags ----
      #pragma unroll 1
      for (int g=0; g<2; g++){
        u32 bB[4];
        #pragma unroll 1
        for (int mm=0;mm<2;mm++){
          // tile (g,mm) A-row cc <-> j-local jp
          const int jp = g*32 + ((cc>>2)<<3) + mm*4 + (cc&3);
          bf16x8 af[4];
          #pragma unroll
          for (int ks=0;ks<4;ks++)
            af[ks] = *(const bf16x8*)&s_hid[buf*8192 + jp*128 + (((ks*4+q) ^ swz(jp))<<3)];

          f32x4 dotC;
          if (p==3){                     // dot(v, Y1): A rows follow same perm
            bf16x8 aY = {0,0,0,0,0,0,0,0};
            if (q==0){
              int jg = ch*64 + jp;
              aY[0]=(short)s_Y1r[0*264+jg];
              aY[1]=(short)s_Y1r[1*264+jg];
              aY[2]=(short)s_Y1r[2*264+jg];
            }
            dotC = __builtin_amdgcn_mfma_f32_16x16x32_bf16(aY, vBf, zf, 0,0,0);
          }

          f32x4 c2 = zf;
          #pragma unroll
          for (int ks=0;ks<4;ks++)
            c2 = __builtin_amdgcn_mfma_f32_16x16x32_bf16(af[ks], w2f[ks], c2, 0,0,0);
          const int dd = dwb+cc;
          float gg[4];
          if (p<3){
            // C row q*4+r of tile (g,mm) <-> j = ch*64 + g*32 + q*8 + mm*4 + r
            const float* hp = hb + (size_t)(ch*64 + g*32 + q*8 + mm*4)*Dd + dd;
            #pragma unroll
            for (int r=0;r<4;r++)
              gg[r] = (c2[r]+b2v) * hp[(size_t)r*Dd];
          } else {
            #pragma unroll
            for (int r=0;r<4;r++)
              gg[r] = (c2[r]+b2v) * dotC[r];
          }
          // lane's j-red B-frag slots: k = q*8 + mm*4 + r
          bB[mm*2+0] = cvtpk(gg[0], gg[1]);
          bB[mm*2+1] = cvtpk(gg[2], gg[3]);
        }
        // ---- j-reduction MFMA over this 32-j group (B-frag from registers) ----
        bf16x8 aR = *(const bf16x8*)(ytrow + ch*64 + g*32 + q*8);
        u32* arp = (u32*)&aR;
        arp[0]&=gmask; arp[1]&=gmask; arp[2]&=gmask; arp[3]&=gmask;
        u32x4 bw = { bB[0], bB[1], bB[2], bB[3] };
        bf16x8 bG = __builtin_bit_cast(bf16x8, bw);
        accred = __builtin_amdgcn_mfma_f32_16x16x32_bf16(aR, bG, accred, 0,0,0);
      }
      buf ^= 1;
    }
  }

  // ---- scatter accred rows -> outputs / LN inputs (complete per wave) ----
  {
    const int d = dwb + cc;
    #pragma unroll
    for (int r=0;r<4;r++){
      const int rw = q*4 + r;
      float val = accred[r];
      if (rw==0)      s_msg[d] = val;
      else if (rw<=3) out_v[(size_t)bi*3*Dd + (size_t)(rw-1)*Dd + d] = val*v_scale[d];
      else if (rw<=8) out_t[(size_t)bi*5*Dd + (size_t)(rw-4)*Dd + d] = val*t_scale[d];
      else if (rw==9) s_xn[d] = val;
    }
  }
  __syncthreads();

  // ---- LayerNorm stats (wave 0) ----
  if (tid < 64){
    float a0=s_msg[tid]+s_xn[tid], a1=s_msg[tid+64]+s_xn[tid+64];
    float s1=a0+a1, s2=a0*a0+a1*a1;
    #pragma unroll
    for (int off=1;off<64;off<<=1){
      s1 += __shfl_xor(s1,off);
      s2 += __shfl_xor(s2,off);
    }
    if (tid==0){
      float m   = s1*(1.f/Dd);
      float var = fmaxf(s2*(1.f/Dd) - m*m, 0.f);
      s_mv[0]=m;
      s_mv[1]=rsqrtf(var+1e-5f);
    }
  }
  __syncthreads();
  if (tid < Dd){
    float msg = s_msg[tid]+s_xn[tid];
    s_xn[tid] = (msg - s_mv[0])*s_mv[1]*ln_g[tid] + ln_b[tid];
  }
  __syncthreads();

  // ---- delta_s = xn @ out_w + out_b (4 k-segments across 512 threads) ----
  {
    int dp = tid & 127, seg = tid >> 7;
    float pa = 0.f;
    #pragma unroll 8
    for (int k=seg*32;k<seg*32+32;k++)
      pa += s_xn[k]*out_w[k*Dd+dp];
    s_part[seg*Dd+dp]=pa;
  }
  __syncthreads();
  if (tid < Dd)
    out_s[(size_t)bi*Dd+tid] = s_part[tid]+s_part[Dd+tid]+s_part[2*Dd+tid]+s_part[3*Dd+tid]+out_b[tid];
}

extern "C" void kernel_launch(void* const* d_in, const int* in_sizes, int n_in,
                              void* d_out, int out_size, void* d_ws, size_t ws_size,
                              hipStream_t stream) {
  const float* node_s = (const float*)d_in[0];
  const float* node_v = (const float*)d_in[1];
  // d_in[2] = node_t (unused by reference)
  const float* rbf    = (const float*)d_in[3];
  const float* r_hat  = (const float*)d_in[4];
  const float* maskp  = (const float*)d_in[5];
  const float* r0w1=(const float*)d_in[6],  *r0b1=(const float*)d_in[7];
  const float* r0w2=(const float*)d_in[8],  *r0b2=(const float*)d_in[9];
  const float* r1w1=(const float*)d_in[10], *r1b1=(const float*)d_in[11];
  const float* r1w2=(const float*)d_in[12], *r1b2=(const float*)d_in[13];
  const float* r2w1=(const float*)d_in[14], *r2b1=(const float*)d_in[15];
  const float* r2w2=(const float*)d_in[16], *r2b2=(const float*)d_in[17];
  const float* r3w1=(const float*)d_in[18], *r3b1=(const float*)d_in[19];
  const float* r3w2=(const float*)d_in[20], *r3b2=(const float*)d_in[21];
  const float* src_w  =(const float*)d_in[22];
  const float* ln_g   =(const float*)d_in[23];
  const float* ln_b   =(const float*)d_in[24];
  const float* out_w  =(const float*)d_in[25];
  const float* out_b  =(const float*)d_in[26];
  const float* v_scale=(const float*)d_in[27];
  const float* t_scale=(const float*)d_in[28];

  float* h_ws = (float*)d_ws;                    // 512*128 f32 = 256 KiB
  float* out_s = (float*)d_out;
  float* out_v = out_s + (size_t)Bb*Nn*Dd;
  float* out_t = out_v + (size_t)Bb*Nn*3*Dd;

  prep_kernel<<<dim3(Bb*Nn + 32), dim3(128), 0, stream>>>(
      node_s, src_w,
      r0w1, r1w1, r2w1, r3w1, r0w2, r1w2, r2w2, r3w2,
      h_ws);
  se3_mfma12<<<dim3(Bb*Nn), dim3(512), 0, stream>>>(
      node_v, rbf, r_hat, maskp,
      r0b1,r0b2, r1b1,r1b2, r2b1,r2b2, r3b1,r3b2,
      ln_g, ln_b, out_w, out_b, v_scale, t_scale,
      h_ws, out_s, out_v, out_t);
}

// Round 9
// 184.476 us; speedup vs baseline: 1.1508x; 1.0184x over previous
//
#include <hip/hip_runtime.h>

#define Bb 2
#define Nn 256
#define Dd 128
#define Rr 32

typedef unsigned short u16;
typedef unsigned int   u32;
typedef __attribute__((ext_vector_type(8))) short bf16x8;
typedef __attribute__((ext_vector_type(4))) float f32x4;
typedef __attribute__((ext_vector_type(2))) u32   u32x2;
typedef __attribute__((ext_vector_type(4))) u32   u32x4;

// one-time bf16-transposed radial weights (fragment-order), filled by prep_kernel
__device__ u16 g_w1t[4*Dd*Rr];   // per p: W1T[dd*32 + kk] = bf16(W1[kk][dd])
__device__ u16 g_w2t[4*Dd*Dd];   // per p: W2T[dd*128 + kk] = bf16(W2[kk][dd])

__device__ __forceinline__ short f2bfs(float f){
  u32 u = __float_as_uint(f);
  u += 0x7FFFu + ((u >> 16) & 1u);   // RNE
  return (short)(u >> 16);
}
__device__ __forceinline__ u16 f2bf(float f){
  u32 u = __float_as_uint(f);
  u += 0x7FFFu + ((u >> 16) & 1u);
  return (u16)(u >> 16);
}
// packed f32x2 -> bf16x2 (RNE), one VALU op
__device__ __forceinline__ u32 cvtpk(float a, float b){
  u32 r;
  asm("v_cvt_pk_bf16_f32 %0, %1, %2" : "=v"(r) : "v"(a), "v"(b));
  return r;
}
// 3-bit LDS granule swizzle for s_hid rows (16B granules, 16 per row)
__device__ __forceinline__ int swz(int j){
  return (j&3) | ((((j>>2)^(j>>3))&1)<<2);
}

// ---- prep: blocks [0,512): h = node_s @ src_w, stored TRANSPOSED h_T[b][d][i]
//      blocks [512,544): weight bf16-transpose
__global__ __launch_bounds__(128) void prep_kernel(
    const float* __restrict__ node_s, const float* __restrict__ src_w,
    const float* __restrict__ r0w1, const float* __restrict__ r1w1,
    const float* __restrict__ r2w1, const float* __restrict__ r3w1,
    const float* __restrict__ r0w2, const float* __restrict__ r1w2,
    const float* __restrict__ r2w2, const float* __restrict__ r3w2,
    float* __restrict__ h_out)
{
  const int bx = blockIdx.x;
  const int t  = threadIdx.x;
  if (bx < Bb*Nn){
    __shared__ float s_row[Dd];
    s_row[t] = node_s[(size_t)bx*Dd + t];
    __syncthreads();
    float acc = 0.f;
    #pragma unroll 8
    for (int k=0;k<Dd;k++) acc += s_row[k]*src_w[k*Dd + t];
    const int b = bx >> 8, i = bx & 255;
    h_out[(size_t)(b*Dd + t)*Nn + i] = acc;       // transposed: [b][d][i]
  } else {
    const int kb = bx - Bb*Nn;          // 0..31
    const int p  = kb >> 3, sl = kb & 7;
    const float* W1 = (p==0)?r0w1:(p==1)?r1w1:(p==2)?r2w1:r3w1;
    const float* W2 = (p==0)?r0w2:(p==1)?r1w2:(p==2)?r2w2:r3w2;
    u16* W1T = g_w1t + p*Dd*Rr;
    u16* W2T = g_w2t + p*Dd*Dd;
    // coalesced reads (linear in), scattered writes (stores don't stall)
    #pragma unroll
    for (int it=0; it<4; it++){
      int in = sl*512 + it*128 + t;                  // in = kk*Dd + dd
      W1T[(in & 127)*Rr + (in >> 7)] = f2bf(W1[in]);
    }
    #pragma unroll
    for (int it=0; it<16; it++){
      int in = sl*2048 + it*128 + t;                 // in = kk*Dd + dd
      W2T[(in & 127)*Dd + (in >> 7)] = f2bf(W2[in]);
    }
  }
}

// ---- main: 8 waves/block, 512 thr, (512,4) [128-reg budget, no spill @ VGPR~52-90].
// Wave w owns d-cols [w*16,+16) and ALL j. SOFTWARE-PIPELINED chunk loop:
// each barrier region contains {GEMM1(t+1) -> buf^1} AND {GEMM2(t) <- buf} so
// waves skew across the SiLU-VALU and MFMA phases instead of phase-locking
// (r8 measured VALUBusy 48% from lockstep). One barrier per chunk. Buffer
// write at t+1 is ordered after its last read (GEMM2 at t-1) by barrier(t).
// GEMM2 m-tiles permuted (tile (g,mm) row x holds j=g*32+(x>>2)*8+mm*4+(x&3))
// so epilogue values land as the j-reduction B-fragment in registers.
__global__ __launch_bounds__(512,4) void se3_mfma13(
    const float* __restrict__ node_v,
    const float* __restrict__ rbf,
    const float* __restrict__ r_hat,
    const float* __restrict__ maskp,
    const float* __restrict__ r0b1, const float* __restrict__ r0b2,
    const float* __restrict__ r1b1, const float* __restrict__ r1b2,
    const float* __restrict__ r2b1, const float* __restrict__ r2b2,
    const float* __restrict__ r3b1, const float* __restrict__ r3b2,
    const float* __restrict__ ln_g, const float* __restrict__ ln_b,
    const float* __restrict__ out_w, const float* __restrict__ out_b,
    const float* __restrict__ v_scale, const float* __restrict__ t_scale,
    const float* __restrict__ h_ws,
    float* __restrict__ out_s, float* __restrict__ out_v, float* __restrict__ out_t)
{
  __shared__ u16   s_rbf[Nn*40];       // 20480: rbf bf16, stride 40 -> 16B-aligned b128
  __shared__ u16   s_hid[2*64*128];    // 32768: double-buffered, swizzled
  __shared__ u16   s_YT[10*264];       //  5280
  __shared__ u16   s_Y1r[3*264];       //  1584
  __shared__ float s_msg[Dd];          //   512
  __shared__ float s_xn[Dd];           //   512
  __shared__ float s_part[4*Dd];       //  2048
  __shared__ float s_mv[2];            //     8  -> total 63192 B (2 blocks/CU)

  const int tid  = threadIdx.x;
  const int bi   = blockIdx.x;            // b*N + i
  const int b    = bi >> 8;
  const int lane = tid & 63;
  const int w    = tid >> 6;              // wave 0..7
  const int q    = lane >> 4;
  const int cc   = lane & 15;
  const int dwb  = w*16;                  // this wave's 16-col d-base

  // ---- setup: stacked-Y rows (mask folded), raw Y1 ----
  if (tid < Nn){
    int j = tid;
    size_t pidx = (size_t)bi*Nn + j;
    float mk = maskp[pidx];
    float x = r_hat[pidx*3+0];
    float y = r_hat[pidx*3+1];
    float z = r_hat[pidx*3+2];
    const float SQ3=1.7320508075688772f;
    const float C15=3.8729833462074170f;
    const float C5H=1.1180339887498949f;
    float y1a=SQ3*x, y1b=SQ3*y, y1c=SQ3*z;
    s_YT[0*264+j]=f2bf(mk);
    s_YT[1*264+j]=f2bf(y1a*mk);
    s_YT[2*264+j]=f2bf(y1b*mk);
    s_YT[3*264+j]=f2bf(y1c*mk);
    s_YT[4*264+j]=f2bf(C15*x*y*mk);
    s_YT[5*264+j]=f2bf(C15*y*z*mk);
    s_YT[6*264+j]=f2bf(C5H*(3.f*z*z-1.f)*mk);
    s_YT[7*264+j]=f2bf(C15*x*z*mk);
    s_YT[8*264+j]=f2bf(0.5f*C15*(x*x-y*y)*mk);
    s_YT[9*264+j]=f2bf(mk);
    s_Y1r[0*264+j]=f2bf(y1a);
    s_Y1r[1*264+j]=f2bf(y1b);
    s_Y1r[2*264+j]=f2bf(y1c);
  }

  const float* rbf_blk = rbf + (size_t)bi*Nn*Rr;
  const float* htb     = h_ws + (size_t)b*Dd*Nn;   // h_T[b][d][i]

  // ---- stage rbf as bf16 (row stride 40): packed pairs ----
  for (int idx=tid; idx<Nn*Rr/2; idx+=512){
    int j = idx >> 4, r2 = (idx & 15)*2;
    const float* src = &rbf_blk[j*Rr + r2];
    float v0 = src[0], v1 = src[1];
    *(u32*)&s_rbf[j*40 + r2] = cvtpk(v0, v1);
  }

  // ---- node_v B-fragment for the dot MFMA (wave's 16 d-cols) ----
  bf16x8 vBf;
  {
    const float* nv = node_v + (size_t)bi*3*Dd;
    int dd = dwb+cc;
    bf16x8 t = {0,0,0,0,0,0,0,0};
    if (q==0){
      t[0]=f2bfs(nv[0*Dd+dd]);
      t[1]=f2bfs(nv[1*Dd+dd]);
      t[2]=f2bfs(nv[2*Dd+dd]);
    }
    vBf=t;
  }

  __syncthreads();                       // setup + staging visible

  const f32x4 zf = {0.f,0.f,0.f,0.f};
  f32x4 accred = zf;
  const u16* ytrow = &s_YT[(cc<10?cc:9)*264];

  // GEMM1 for chunk chn of its p -> s_hid[bufn]
  auto do_gemm1 = [&](int chn, int bufn, const bf16x8& w1f_, const f32x4& b1v_){
    #pragma unroll 1
    for (int jt=0;jt<4;jt++){
      const int jrow = jt*16 + cc;                   // j within chunk
      bf16x8 rbff = *(const bf16x8*)&s_rbf[(chn*64 + jrow)*40 + q*8];
      f32x4 hc = __builtin_amdgcn_mfma_f32_16x16x32_bf16(w1f_, rbff, zf, 0,0,0);
      float s[4];
      #pragma unroll
      for (int r=0;r<4;r++){
        float x  = hc[r] + b1v_[r];
        float e  = __expf(-x);
        s[r]     = x*__builtin_amdgcn_rcpf(1.f+e);
      }
      u32x2 pk = { cvtpk(s[0], s[1]), cvtpk(s[2], s[3]) };
      const int c0 = w*2 + (q>>1);                   // 16B d-granule 0..15
      *(u32x2*)&s_hid[bufn*8192 + jrow*128 + ((c0 ^ swz(jrow))<<3) + (q&1)*4] = pk;
    }
  };

  // pipeline state
  int buf = 0;
  bf16x8 w1f;  f32x4 b1v4;          // weights for the NEXT pending GEMM1 (its p)
  bf16x8 w2f[4]; float b2v; u32 gmask;

  // prologue: p0 GEMM1 weights + chunk 0
  w1f  = *(const bf16x8*)&g_w1t[(dwb+cc)*Rr + q*8];
  b1v4 = *(const f32x4*)&r0b1[dwb + q*4];
  do_gemm1(0, 0, w1f, b1v4);

  #pragma unroll 1
  for (int t=0;t<16;t++){
    const int p = t>>2, ch = t&3;
    if (ch==0){
      // load GEMM2-side weights for this p (before barrier; GEMM2(t-1) done)
      const u16* W2T = g_w2t + p*Dd*Dd;
      #pragma unroll
      for (int ks=0;ks<4;ks++)
        w2f[ks] = *(const bf16x8*)&W2T[(dwb+cc)*Dd + ks*32 + q*8];
      const float* B2p = (p==0)?r0b2:(p==1)?r1b2:(p==2)?r2b2:r3b2;
      b2v = B2p[dwb + cc];
      const int lo = (p==0)?0:(p==1)?1:(p==2)?4:9;
      const int hi = (p==0)?0:(p==1)?3:(p==2)?8:9;
      gmask = (cc>=lo && cc<=hi) ? 0xFFFFFFFFu : 0u;
    }
    __syncthreads();                 // hid[buf] ready; orders buf^1 writes after t-1 reads

    if (t<15){
      const int tn=t+1, pn=tn>>2, chn=tn&3;
      if (chn==0){                   // prefetch GEMM1 weights for next p
        w1f  = *(const bf16x8*)&g_w1t[pn*Dd*Rr + (dwb+cc)*Rr + q*8];
        const float* B1p = (pn==1)?r1b1:(pn==2)?r2b1:r3b1;
        b1v4 = *(const f32x4*)&B1p[dwb + q*4];
      }
      do_gemm1(chn, buf^1, w1f, b1v4);
    }

    // ---- GEMM2(t) on buf: 4 permuted tiles + epilogue -> in-register B-frags ----
    #pragma unroll 1
    for (int g=0; g<2; g++){
      u32 bB[4];
      #pragma unroll 1
      for (int mm=0;mm<2;mm++){
        const int jp = g*32 + ((cc>>2)<<3) + mm*4 + (cc&3);   // tile (g,mm) A-row cc
        bf16x8 af[4];
        #pragma unroll
        for (int ks=0;ks<4;ks++)
          af[ks] = *(const bf16x8*)&s_hid[buf*8192 + jp*128 + (((ks*4+q) ^ swz(jp))<<3)];

        f32x4 dotC;
        if (p==3){                   // dot(v, Y1): A rows follow same perm
          bf16x8 aY = {0,0,0,0,0,0,0,0};
          if (q==0){
            int jg = ch*64 + jp;
            aY[0]=(short)s_Y1r[0*264+jg];
            aY[1]=(short)s_Y1r[1*264+jg];
            aY[2]=(short)s_Y1r[2*264+jg];
          }
          dotC = __builtin_amdgcn_mfma_f32_16x16x32_bf16(aY, vBf, zf, 0,0,0);
        }

        f32x4 c2 = zf;
        #pragma unroll
        for (int ks=0;ks<4;ks++)
          c2 = __builtin_amdgcn_mfma_f32_16x16x32_bf16(af[ks], w2f[ks], c2, 0,0,0);
        float gg[4];
        if (p<3){
          // C row q*4+r of tile (g,mm) <-> j = ch*64+g*32+q*8+mm*4+r: contiguous in h_T
          f32x4 hq = *(const f32x4*)&htb[(size_t)(dwb+cc)*Nn + ch*64 + g*32 + q*8 + mm*4];
          #pragma unroll
          for (int r=0;r<4;r++)
            gg[r] = (c2[r]+b2v) * hq[r];
        } else {
          #pragma unroll
          for (int r=0;r<4;r++)
            gg[r] = (c2[r]+b2v) * dotC[r];
        }
        // lane's j-red B-frag slots: k = q*8 + mm*4 + r
        bB[mm*2+0] = cvtpk(gg[0], gg[1]);
        bB[mm*2+1] = cvtpk(gg[2], gg[3]);
      }
      // ---- j-reduction MFMA over this 32-j group (B-frag from registers) ----
      bf16x8 aR = *(const bf16x8*)(ytrow + ch*64 + g*32 + q*8);
      u32* arp = (u32*)&aR;
      arp[0]&=gmask; arp[1]&=gmask; arp[2]&=gmask; arp[3]&=gmask;
      u32x4 bw = { bB[0], bB[1], bB[2], bB[3] };
      bf16x8 bG = __builtin_bit_cast(bf16x8, bw);
      accred = __builtin_amdgcn_mfma_f32_16x16x32_bf16(aR, bG, accred, 0,0,0);
    }
    buf ^= 1;
  }

  // ---- scatter accred rows -> outputs / LN inputs (complete per wave) ----
  {
    const int d = dwb + cc;
    #pragma unroll
    for (int r=0;r<4;r++){
      const int rw = q*4 + r;
      float val = accred[r];
      if (rw==0)      s_msg[d] = val;
      else if (rw<=3) out_v[(size_t)bi*3*Dd + (size_t)(rw-1)*Dd + d] = val*v_scale[d];
      else if (rw<=8) out_t[(size_t)bi*5*Dd + (size_t)(rw-4)*Dd + d] = val*t_scale[d];
      else if (rw==9) s_xn[d] = val;
    }
  }
  __syncthreads();

  // ---- LayerNorm stats (wave 0) ----
  if (tid < 64){
    float a0=s_msg[tid]+s_xn[tid], a1=s_msg[tid+64]+s_xn[tid+64];
    float s1=a0+a1, s2=a0*a0+a1*a1;
    #pragma unroll
    for (int off=1;off<64;off<<=1){
      s1 += __shfl_xor(s1,off);
      s2 += __shfl_xor(s2,off);
    }
    if (tid==0){
      float m   = s1*(1.f/Dd);
      float var = fmaxf(s2*(1.f/Dd) - m*m, 0.f);
      s_mv[0]=m;
      s_mv[1]=rsqrtf(var+1e-5f);
    }
  }
  __syncthreads();
  if (tid < Dd){
    float msg = s_msg[tid]+s_xn[tid];
    s_xn[tid] = (msg - s_mv[0])*s_mv[1]*ln_g[tid] + ln_b[tid];
  }
  __syncthreads();

  // ---- delta_s = xn @ out_w + out_b (4 k-segments across 512 threads) ----
  {
    int dp = tid & 127, seg = tid >> 7;
    float pa = 0.f;
    #pragma unroll 8
    for (int k=seg*32;k<seg*32+32;k++)
      pa += s_xn[k]*out_w[k*Dd+dp];
    s_part[seg*Dd+dp]=pa;
  }
  __syncthreads();
  if (tid < Dd)
    out_s[(size_t)bi*Dd+tid] = s_part[tid]+s_part[Dd+tid]+s_part[2*Dd+tid]+s_part[3*Dd+tid]+out_b[tid];
}

extern "C" void kernel_launch(void* const* d_in, const int* in_sizes, int n_in,
                              void* d_out, int out_size, void* d_ws, size_t ws_size,
                              hipStream_t stream) {
  const float* node_s = (const float*)d_in[0];
  const float* node_v = (const float*)d_in[1];
  // d_in[2] = node_t (unused by reference)
  const float* rbf    = (const float*)d_in[3];
  const float* r_hat  = (const float*)d_in[4];
  const float* maskp  = (const float*)d_in[5];
  const float* r0w1=(const float*)d_in[6],  *r0b1=(const float*)d_in[7];
  const float* r0w2=(const float*)d_in[8],  *r0b2=(const float*)d_in[9];
  const float* r1w1=(const float*)d_in[10], *r1b1=(const float*)d_in[11];
  const float* r1w2=(const float*)d_in[12], *r1b2=(const float*)d_in[13];
  const float* r2w1=(const float*)d_in[14], *r2b1=(const float*)d_in[15];
  const float* r2w2=(const float*)d_in[16], *r2b2=(const float*)d_in[17];
  const float* r3w1=(const float*)d_in[18], *r3b1=(const float*)d_in[19];
  const float* r3w2=(const float*)d_in[20], *r3b2=(const float*)d_in[21];
  const float* src_w  =(const float*)d_in[22];
  const float* ln_g   =(const float*)d_in[23];
  const float* ln_b   =(const float*)d_in[24];
  const float* out_w  =(const float*)d_in[25];
  const float* out_b  =(const float*)d_in[26];
  const float* v_scale=(const float*)d_in[27];
  const float* t_scale=(const float*)d_in[28];

  float* h_ws = (float*)d_ws;                    // h_T: 2*128*256 f32 = 256 KiB
  float* out_s = (float*)d_out;
  float* out_v = out_s + (size_t)Bb*Nn*Dd;
  float* out_t = out_v + (size_t)Bb*Nn*3*Dd;

  prep_kernel<<<dim3(Bb*Nn + 32), dim3(128), 0, stream>>>(
      node_s, src_w,
      r0w1, r1w1, r2w1, r3w1, r0w2, r1w2, r2w2, r3w2,
      h_ws);
  se3_mfma13<<<dim3(Bb*Nn), dim3(512), 0, stream>>>(
      node_v, rbf, r_hat, maskp,
      r0b1,r0b2, r1b1,r1b2, r2b1,r2b2, r3b1,r3b2,
      ln_g, ln_b, out_w, out_b, v_scale, t_scale,
      h_ws, out_s, out_v, out_t);
}